// Round 3
// baseline (280.213 us; speedup 1.0000x reference)
//
#include <hip/hip_runtime.h>
#include <math.h>

#define NB 32
#define NB2 1024
#define EPS 1e-5f

// Joint histogram, contiguous-partition version.
// Each block owns a private contiguous chunk so each cache line is pulled
// into exactly ONE XCD's L2 (R1's whole-grid stride made all 8 XCDs fetch
// the full 268 MB -> ~2.1 GB of fabric fill, the suspected 100us wall).
__global__ __launch_bounds__(256, 8) void hist_kernel(const float4* __restrict__ I4,
                                                      const float4* __restrict__ J4,
                                                      unsigned int* __restrict__ hist,
                                                      int n4, int chunk) {
    __shared__ unsigned int lh[NB2];
    const int t = threadIdx.x;
    for (int i = t; i < NB2; i += 256) lh[i] = 0u;
    __syncthreads();

    const float s = 31.0f / 255.0f;  // bit-exact vs /255*31+round (absmax 0 in R0/R1)
    const int beg = blockIdx.x * chunk;
    const int end = min(beg + chunk, n4);

    int base = beg;
    for (; base + 1024 <= end; base += 1024) {
        const int i = base + t;
        // 8 independent loads in flight before any dependent use
        float4 a0 = I4[i];
        float4 a1 = I4[i + 256];
        float4 a2 = I4[i + 512];
        float4 a3 = I4[i + 768];
        float4 b0 = J4[i];
        float4 b1 = J4[i + 256];
        float4 b2 = J4[i + 512];
        float4 b3 = J4[i + 768];
        atomicAdd(&lh[((int)rintf(a0.x * s) << 5) | (int)rintf(b0.x * s)], 1u);
        atomicAdd(&lh[((int)rintf(a0.y * s) << 5) | (int)rintf(b0.y * s)], 1u);
        atomicAdd(&lh[((int)rintf(a0.z * s) << 5) | (int)rintf(b0.z * s)], 1u);
        atomicAdd(&lh[((int)rintf(a0.w * s) << 5) | (int)rintf(b0.w * s)], 1u);
        atomicAdd(&lh[((int)rintf(a1.x * s) << 5) | (int)rintf(b1.x * s)], 1u);
        atomicAdd(&lh[((int)rintf(a1.y * s) << 5) | (int)rintf(b1.y * s)], 1u);
        atomicAdd(&lh[((int)rintf(a1.z * s) << 5) | (int)rintf(b1.z * s)], 1u);
        atomicAdd(&lh[((int)rintf(a1.w * s) << 5) | (int)rintf(b1.w * s)], 1u);
        atomicAdd(&lh[((int)rintf(a2.x * s) << 5) | (int)rintf(b2.x * s)], 1u);
        atomicAdd(&lh[((int)rintf(a2.y * s) << 5) | (int)rintf(b2.y * s)], 1u);
        atomicAdd(&lh[((int)rintf(a2.z * s) << 5) | (int)rintf(b2.z * s)], 1u);
        atomicAdd(&lh[((int)rintf(a2.w * s) << 5) | (int)rintf(b2.w * s)], 1u);
        atomicAdd(&lh[((int)rintf(a3.x * s) << 5) | (int)rintf(b3.x * s)], 1u);
        atomicAdd(&lh[((int)rintf(a3.y * s) << 5) | (int)rintf(b3.y * s)], 1u);
        atomicAdd(&lh[((int)rintf(a3.z * s) << 5) | (int)rintf(b3.z * s)], 1u);
        atomicAdd(&lh[((int)rintf(a3.w * s) << 5) | (int)rintf(b3.w * s)], 1u);
    }
    // tail (not taken for n4 = 2^23, grid 2048, chunk 4096; kept for generality)
    for (int i = base + t; i < end; i += 256) {
        float4 a = I4[i];
        float4 b = J4[i];
        atomicAdd(&lh[((int)rintf(a.x * s) << 5) | (int)rintf(b.x * s)], 1u);
        atomicAdd(&lh[((int)rintf(a.y * s) << 5) | (int)rintf(b.y * s)], 1u);
        atomicAdd(&lh[((int)rintf(a.z * s) << 5) | (int)rintf(b.z * s)], 1u);
        atomicAdd(&lh[((int)rintf(a.w * s) << 5) | (int)rintf(b.w * s)], 1u);
    }
    __syncthreads();

    for (int k = t; k < NB2; k += 256) {
        unsigned int c = lh[k];
        if (c) atomicAdd(&hist[k], c);
    }
}

// probs -> marginals -> MI -> sigmoid(-mi). One block, 1024 threads.
__global__ __launch_bounds__(1024) void mi_kernel(const unsigned int* __restrict__ hist,
                                                  float* __restrict__ out,
                                                  float invN) {
    __shared__ float jp[NB2];
    __shared__ float Ip[NB];
    __shared__ float Jp[NB];
    __shared__ float wsum[16];

    const int t = threadIdx.x;
    float p = (float)hist[t] * invN;  // invN = 2^-25: exact
    jp[t] = p;
    __syncthreads();

    if (t < NB) {  // row sums (marginal over J)
        float acc = 0.0f;
        for (int c = 0; c < NB; ++c) acc += jp[(t << 5) | c];
        Ip[t] = acc;
    } else if (t < 2 * NB) {  // col sums (marginal over I)
        int c = t - NB;
        float acc = 0.0f;
        for (int r = 0; r < NB; ++r) acc += jp[(r << 5) | c];
        Jp[c] = acc;
    }
    __syncthreads();

    float term = p * (logf(p + EPS) - logf(Ip[t >> 5] + EPS) - logf(Jp[t & 31] + EPS));

    for (int off = 32; off > 0; off >>= 1) term += __shfl_down(term, off, 64);
    const int wave = t >> 6;
    if ((t & 63) == 0) wsum[wave] = term;
    __syncthreads();

    if (t == 0) {
        float mi = 0.0f;
        for (int w = 0; w < 16; ++w) mi += wsum[w];
        out[0] = 1.0f / (1.0f + expf(mi));  // sigmoid(-mi)
    }
}

extern "C" void kernel_launch(void* const* d_in, const int* in_sizes, int n_in,
                              void* d_out, int out_size, void* d_ws, size_t ws_size,
                              hipStream_t stream) {
    const float4* I4 = (const float4*)d_in[0];
    const float4* J4 = (const float4*)d_in[1];
    unsigned int* hist = (unsigned int*)d_ws;  // 4 KiB of workspace
    const int n = in_sizes[0];                 // 33,554,432
    const int n4 = n >> 2;
    const int grid = 2048;
    const int chunk = (n4 + grid - 1) / grid;  // 4096: contiguous slice per block

    hipMemsetAsync(hist, 0, NB2 * sizeof(unsigned int), stream);
    hist_kernel<<<grid, 256, 0, stream>>>(I4, J4, hist, n4, chunk);
    mi_kernel<<<1, 1024, 0, stream>>>(hist, (float*)d_out, 1.0f / (float)n);
}